// Round 5
// baseline (943.061 us; speedup 1.0000x reference)
//
#include <hip/hip_runtime.h>
#include <hip/hip_bf16.h>
#include <cstdint>
#include <cstddef>

#define CDIM 128
#define NCELLS 100000

typedef __attribute__((ext_vector_type(8))) short short8;
typedef __attribute__((ext_vector_type(4))) float f32x4;

__device__ __forceinline__ unsigned short f2bf(float f) {
    unsigned u = __float_as_uint(f);
    unsigned r = u + 0x7FFFu + ((u >> 16) & 1u);
    return (unsigned short)(r >> 16);
}
__device__ __forceinline__ float bf2f(unsigned short u) {
    return __uint_as_float(((unsigned)u) << 16);
}
// packed f32x2 -> bf16x2 (1 instr, RNE)
__device__ __forceinline__ unsigned pkbf(float lo, float hi) {
    unsigned r;
    asm("v_cvt_pk_bf16_f32 %0, %1, %2" : "=v"(r) : "v"(lo), "v"(hi));
    return r;
}
__device__ __forceinline__ unsigned short cvt1bf(float x) {
    return (unsigned short)(pkbf(x, x) & 0xffffu);
}
__device__ __forceinline__ float sigf(float x) { return 1.f / (1.f + __expf(-x)); }
__device__ __forceinline__ float siluf(float x) { return x * sigf(x); }

// async global->LDS, 16B per lane. LDS dest = wave-uniform base + lane*16.
__device__ __forceinline__ void load_lds16(const void* g, void* ldsbase, int lane) {
    __builtin_amdgcn_global_load_lds(
        (const __attribute__((address_space(1))) unsigned int*)(uintptr_t)g,
        (__attribute__((address_space(3))) unsigned int*)(uintptr_t)ldsbase,
        16, 0, 0);
}

// ---------------------------------------------------------------------------
// Weight prep: fp32 (fin x 128) -> bf16 MFMA B-fragment order.
// frag f = cg*ktc + kt holds, lane l: W[kt*32+(l>>4)*8+i][cg*16+(l&15)].
// ---------------------------------------------------------------------------
struct PrepArgs {
    const float* src[14];
    int dstoff[14];
    int fin[14];
    int ktc[14];
    int tend[14];
};

__global__ void prep_kernel(PrepArgs pa, unsigned short* __restrict__ wb) {
    int tile = blockIdx.x;
    int m = 0;
    while (tile >= pa.tend[m]) m++;
    int local = tile - (m == 0 ? 0 : pa.tend[m - 1]);
    int ktc = pa.ktc[m];
    int ct = local / ktc;
    int kt = local % ktc;
    int l = threadIdx.x;   // 64
    unsigned short* dst = wb + pa.dstoff[m] + (size_t)local * 512 + l * 8;
    const float* src = pa.src[m];
    int fin = pa.fin[m];
    int col = ct * 16 + (l & 15);
#pragma unroll
    for (int i = 0; i < 8; i++) {
        int k = kt * 32 + (l >> 4) * 8 + i;
        float v = (k < fin) ? src[(size_t)k * CDIM + col] : 0.f;
        dst[i] = f2bf(v);
    }
}

// ---------------------------------------------------------------------------
// CSR build: fused histogram -> scan -> fused rank
// ---------------------------------------------------------------------------
__global__ void hist4_kernel(const int* __restrict__ r0, const int* __restrict__ r1,
                             const int* __restrict__ r2, const int* __restrict__ r3,
                             int E0, int E1, int E2, int E3, int* __restrict__ bins) {
    int i = blockIdx.x * blockDim.x + threadIdx.x;
    const int c1 = E0, c2 = c1 + E1, c3 = c2 + E2, c4 = c3 + E3;
    if (i >= c4) return;
    const int* r; int* b; int j;
    if (i < c1)      { r = r0; j = i;      b = bins; }
    else if (i < c2) { r = r1; j = i - c1; b = bins + (size_t)NCELLS; }
    else if (i < c3) { r = r2; j = i - c2; b = bins + (size_t)2 * NCELLS; }
    else             { r = r3; j = i - c3; b = bins + (size_t)3 * NCELLS; }
    atomicAdd(&b[r[j]], 1);
}

__global__ __launch_bounds__(1024)
void scan_kernel(const int* __restrict__ bins, int* __restrict__ offs, int NB) {
    __shared__ int wsum[16];
    __shared__ int run_s;
    const int r = blockIdx.x, t = threadIdx.x;
    const int lane = t & 63, w = t >> 6;
    const int* b = bins + (size_t)r * NB;
    int* o = offs + (size_t)r * (NB + 1);
    if (t == 0) run_s = 0;
    __syncthreads();
    for (int base = 0; base < NB; base += 1024) {
        int v = (base + t < NB) ? b[base + t] : 0;
        int x = v;
#pragma unroll
        for (int d = 1; d < 64; d <<= 1) {
            int y = __shfl_up(x, (unsigned)d, 64);
            if (lane >= d) x += y;
        }
        if (lane == 63) wsum[w] = x;
        __syncthreads();
        if (w == 0) {
            int s = (lane < 16) ? wsum[lane] : 0;
#pragma unroll
            for (int d = 1; d < 16; d <<= 1) {
                int y = __shfl_up(s, (unsigned)d, 64);
                if (lane >= d) s += y;
            }
            if (lane < 16) wsum[lane] = s;
        }
        __syncthreads();
        int woff = (w == 0) ? 0 : wsum[w - 1];
        int run = run_s;
        if (base + t < NB) o[base + t] = run + woff + x - v;
        int tot = wsum[15];
        __syncthreads();
        if (t == 0) run_s = run + tot;
        __syncthreads();
    }
    if (t == 0) o[NB] = run_s;
}

__global__ void rank4_kernel(const int* __restrict__ r0, const int* __restrict__ r1,
                             const int* __restrict__ r2, const int* __restrict__ r3,
                             int E0, int E1, int E2, int E3,
                             const int* __restrict__ offs, int* __restrict__ cur,
                             int* __restrict__ p0, int* __restrict__ p1,
                             int* __restrict__ p2, int* __restrict__ p3) {
    int i = blockIdx.x * blockDim.x + threadIdx.x;
    const int c1 = E0, c2 = c1 + E1, c3 = c2 + E2, c4 = c3 + E3;
    if (i >= c4) return;
    const int* r; const int* o; int* c; int* p; int j;
    if (i < c1)      { r = r0; j = i;      o = offs;                         c = cur;                      p = p0; }
    else if (i < c2) { r = r1; j = i - c1; o = offs + (size_t)(NCELLS + 1);  c = cur + (size_t)NCELLS;     p = p1; }
    else if (i < c3) { r = r2; j = i - c2; o = offs + (size_t)2*(NCELLS+1);  c = cur + (size_t)2 * NCELLS; p = p2; }
    else             { r = r3; j = i - c3; o = offs + (size_t)3*(NCELLS+1);  c = cur + (size_t)3 * NCELLS; p = p3; }
    int v = r[j];
    p[j] = o[v] + atomicAdd(&c[v], 1);
}

// ---------------------------------------------------------------------------
// P-GEMM: P = f(f32, NxC) @ W1[koff-slice] (+ optional b1), stored bf16 row-major.
// W1T frags: idx = (cg*9 + kt + koff), kt=0..3.
// ---------------------------------------------------------------------------
__global__ __launch_bounds__(256, 4)
void pgemm_kernel(const float* __restrict__ f, const unsigned short* __restrict__ W1T,
                  int koff, const float* __restrict__ b1,
                  unsigned short* __restrict__ P)
{
    constexpr int AS = 136;   // shorts; 272B rows (16B aligned)
    __shared__ unsigned short A[64 * AS];

    const int t = threadIdx.x;
    const int n0 = blockIdx.x * 64;
    {
        const int rl = t >> 2, q = t & 3;
        int n = n0 + rl; n = (n < NCELLS) ? n : (NCELLS - 1);
        const float4* sp = (const float4*)(f + (size_t)n * CDIM + q * 32);
        unsigned short* arow = A + rl * AS + q * 32;
#pragma unroll
        for (int i = 0; i < 4; i++) {
            float4 a = sp[2 * i], b = sp[2 * i + 1];
            uint4 o;
            o.x = pkbf(a.x, a.y); o.y = pkbf(a.z, a.w);
            o.z = pkbf(b.x, b.y); o.w = pkbf(b.z, b.w);
            *(uint4*)(arow + i * 8) = o;
        }
    }
    __syncthreads();

    const int l = t & 63, w = t >> 6;
    const int lr = l & 15, lg = l >> 4;
    const int wr = (w & 1) * 32, wc = (w >> 1) * 64;

    f32x4 acc[2][4];
#pragma unroll
    for (int mt = 0; mt < 2; mt++)
#pragma unroll
        for (int ct = 0; ct < 4; ct++) acc[mt][ct] = (f32x4){0.f, 0.f, 0.f, 0.f};

#pragma unroll
    for (int kt = 0; kt < 4; ++kt) {
        short8 av[2];
#pragma unroll
        for (int mt = 0; mt < 2; mt++)
            av[mt] = *(const short8*)(A + (wr + mt * 16 + lr) * AS + kt * 32 + lg * 8);
#pragma unroll
        for (int ct = 0; ct < 4; ct++) {
            const int cg = (wc >> 4) + ct;
            short8 bv = *(const short8*)(W1T + ((size_t)(cg * 9 + kt + koff) * 64 + l) * 8);
            acc[0][ct] = __builtin_amdgcn_mfma_f32_16x16x32_bf16(av[0], bv, acc[0][ct], 0, 0, 0);
            acc[1][ct] = __builtin_amdgcn_mfma_f32_16x16x32_bf16(av[1], bv, acc[1][ct], 0, 0, 0);
        }
    }

    float b1c[4];
#pragma unroll
    for (int ct = 0; ct < 4; ct++) b1c[ct] = b1 ? b1[wc + ct * 16 + lr] : 0.f;

#pragma unroll
    for (int mt = 0; mt < 2; mt++)
#pragma unroll
        for (int j = 0; j < 4; j++) {
            const int row = wr + mt * 16 + lg * 4 + j;
            const int n2  = n0 + row;
            if (n2 < NCELLS) {
#pragma unroll
                for (int ct = 0; ct < 4; ct++)
                    P[(size_t)n2 * CDIM + wc + ct * 16 + lr] = cvt1bf(acc[mt][ct][j] + b1c[ct]);
            }
        }
}

// ---------------------------------------------------------------------------
// EConv v4: per block 64 edges.
//   stage Ps[send],Pt[recv] rows async into 2 swizzled LDS tiles,
//   inv-only MFMA (kt=8), epilogue y = silu(Ps+Pt+inv_acc) in-place,
//   layer-2 MFMA, gate, msg[pos[e]] write.
// LDS slot swizzle: LDS[row, s] = G[row, s ^ (row&7)]  (16B slots, s=0..15)
// ---------------------------------------------------------------------------
template <int NINV>
__global__ __launch_bounds__(256, 4)
void econv_kernel(const unsigned short* __restrict__ Ps, const unsigned short* __restrict__ Pt,
                  const int* __restrict__ send, const int* __restrict__ recv,
                  const float* __restrict__ inv,
                  const unsigned short* __restrict__ W1T,
                  const unsigned short* __restrict__ W2T, const float* __restrict__ b2,
                  const float* __restrict__ Wg, const float* __restrict__ bg,
                  const int* __restrict__ pos, unsigned short* __restrict__ msg, int E)
{
    __shared__ unsigned short PsL[64 * 128];   // also Y (in-place)
    __shared__ unsigned short PtL[64 * 128];   // also O
    __shared__ unsigned short Ainv[64 * 40];
    __shared__ float gpart[64];
    __shared__ int   posl[64];

    const int t = threadIdx.x, l = t & 63, w = t >> 6;
    const int e0 = blockIdx.x * 64;

    // ---- async stage: wave w stages rows w*16..w*16+15 (4 rows / instr) ----
    {
        const int slot = l & 15;
        const int rsub = l >> 4;
#pragma unroll
        for (int i = 0; i < 4; i++) {
            const int r = w * 16 + i * 4 + rsub;
            int e = e0 + r; e = (e < E) ? e : (E - 1);
            const int ss = slot ^ (r & 7);
            load_lds16(Ps + (size_t)send[e] * CDIM + ss * 8, PsL + (w * 16 + i * 4) * 128, l);
            load_lds16(Pt + (size_t)recv[e] * CDIM + ss * 8, PtL + (w * 16 + i * 4) * 128, l);
        }
    }
    if (t < 64) {
        int e = e0 + t; e = (e < E) ? e : (E - 1);
        posl[t]  = pos[e];
        gpart[t] = 0.f;
        unsigned short* ar = Ainv + t * 40;
#pragma unroll
        for (int j = 0; j < NINV; j++) ar[j] = cvt1bf(inv[(size_t)e * NINV + j]);
#pragma unroll
        for (int j = NINV; j < 32; j++) ar[j] = 0;
    }
    __syncthreads();

    const int lr = l & 15, lg = l >> 4;
    const int wr = (w & 1) * 32;
    const int wc = (w >> 1) * 64;

    // ---- layer 1: inv-only MFMA (kt = 8 frags of W1T) ----
    f32x4 a1[2][4];
#pragma unroll
    for (int mt = 0; mt < 2; mt++)
#pragma unroll
        for (int ct = 0; ct < 4; ct++) a1[mt][ct] = (f32x4){0.f, 0.f, 0.f, 0.f};
    {
        short8 av[2];
#pragma unroll
        for (int mt = 0; mt < 2; mt++)
            av[mt] = *(const short8*)(Ainv + (wr + mt * 16 + lr) * 40 + lg * 8);
#pragma unroll
        for (int ct = 0; ct < 4; ct++) {
            const int cg = (wc >> 4) + ct;
            short8 bv = *(const short8*)(W1T + ((size_t)(cg * 9 + 8) * 64 + l) * 8);
            a1[0][ct] = __builtin_amdgcn_mfma_f32_16x16x32_bf16(av[0], bv, a1[0][ct], 0, 0, 0);
            a1[1][ct] = __builtin_amdgcn_mfma_f32_16x16x32_bf16(av[1], bv, a1[1][ct], 0, 0, 0);
        }
    }

    // ---- epilogue: y = silu(Ps + Pt + inv_acc), Y overwrites PsL in place ----
#pragma unroll
    for (int ct = 0; ct < 4; ct++) {
        const int col = wc + ct * 16 + lr;
#pragma unroll
        for (int mt = 0; mt < 2; mt++)
#pragma unroll
            for (int j = 0; j < 4; j++) {
                const int row = wr + mt * 16 + lg * 4 + j;
                const int sc  = col ^ ((row & 7) << 3);
                const int idx = row * 128 + sc;
                float y = bf2f(PsL[idx]) + bf2f(PtL[idx]) + a1[mt][ct][j];
                PsL[idx] = cvt1bf(siluf(y));
            }
    }
    __syncthreads();

    // ---- layer 2: Y(64x128) @ W2(128x128) ----
    f32x4 a2[2][4];
#pragma unroll
    for (int mt = 0; mt < 2; mt++)
#pragma unroll
        for (int ct = 0; ct < 4; ct++) a2[mt][ct] = (f32x4){0.f, 0.f, 0.f, 0.f};

#pragma unroll
    for (int kt = 0; kt < 4; ++kt) {
        short8 av[2];
#pragma unroll
        for (int mt = 0; mt < 2; mt++) {
            const int row = wr + mt * 16 + lr;
            const int sl  = (kt * 4 + lg) ^ (row & 7);
            av[mt] = *(const short8*)(PsL + row * 128 + sl * 8);
        }
#pragma unroll
        for (int ct = 0; ct < 4; ct++) {
            const int cg = (wc >> 4) + ct;
            short8 bv = *(const short8*)(W2T + ((size_t)(cg * 4 + kt) * 64 + l) * 8);
            a2[0][ct] = __builtin_amdgcn_mfma_f32_16x16x32_bf16(av[0], bv, a2[0][ct], 0, 0, 0);
            a2[1][ct] = __builtin_amdgcn_mfma_f32_16x16x32_bf16(av[1], bv, a2[1][ct], 0, 0, 0);
        }
    }

    float wg[4], b2c[4];
#pragma unroll
    for (int ct = 0; ct < 4; ct++) {
        const int col = wc + ct * 16 + lr;
        wg[ct]  = Wg[col];
        b2c[ct] = b2[col];
    }
#pragma unroll
    for (int mt = 0; mt < 2; mt++)
#pragma unroll
        for (int ct = 0; ct < 4; ct++)
#pragma unroll
            for (int j = 0; j < 4; j++)
                a2[mt][ct][j] = siluf(a2[mt][ct][j] + b2c[ct]);

#pragma unroll
    for (int mt = 0; mt < 2; mt++)
#pragma unroll
        for (int j = 0; j < 4; j++) {
            float p = a2[mt][0][j] * wg[0] + a2[mt][1][j] * wg[1] +
                      a2[mt][2][j] * wg[2] + a2[mt][3][j] * wg[3];
            p += __shfl_xor(p, 1, 16);
            p += __shfl_xor(p, 2, 16);
            p += __shfl_xor(p, 4, 16);
            p += __shfl_xor(p, 8, 16);
            if (lr == 0) atomicAdd(&gpart[wr + mt * 16 + lg * 4 + j], p);
        }
    __syncthreads();   // Y reads + gate partials complete; O overwrites PtL

    const float bgs = bg[0];
#pragma unroll
    for (int mt = 0; mt < 2; mt++)
#pragma unroll
        for (int j = 0; j < 4; j++) {
            const int row = wr + mt * 16 + lg * 4 + j;
            const float g = sigf(gpart[row] + bgs);
#pragma unroll
            for (int ct = 0; ct < 4; ct++) {
                const int col = wc + ct * 16 + lr;
                PtL[row * 128 + (col ^ ((row & 7) << 3))] = cvt1bf(a2[mt][ct][j] * g);
            }
        }
    __syncthreads();

    // ---- cooperative write to sorted slot ----
    {
        const int row = t >> 2, q = t & 3;
        if (e0 + row < E) {
            unsigned short* dst = msg + (size_t)posl[row] * CDIM + q * 32;
#pragma unroll
            for (int i = 0; i < 4; i++) {
                const int sl = (q * 4 + i) ^ (row & 7);
                *(uint4*)(dst + i * 8) = *(const uint4*)(PtL + row * 128 + sl * 8);
            }
        }
    }
}

// ---------------------------------------------------------------------------
// Update MLP with fused, pipelined segment-sum:
// out = f + silu([f | silu(sum m1) | silu(sum m2)] @ W1 + b1) @ W2 + b2
// ---------------------------------------------------------------------------
__device__ __forceinline__ void accum8(float* a, uint4 v) {
    const unsigned wv[4] = {v.x, v.y, v.z, v.w};
#pragma unroll
    for (int i = 0; i < 4; i++) {
        a[2 * i + 0] += __uint_as_float(wv[i] << 16);
        a[2 * i + 1] += __uint_as_float(wv[i] & 0xffff0000u);
    }
}

template <int F>
__global__ __launch_bounds__(256, F == 3 ? 3 : 4)
void update_kernel(const float* __restrict__ f,
                   const unsigned short* __restrict__ m1, const int* __restrict__ o1,
                   const unsigned short* __restrict__ m2, const int* __restrict__ o2,
                   const unsigned short* __restrict__ W1T, const float* __restrict__ b1,
                   const unsigned short* __restrict__ W2T, const float* __restrict__ b2,
                   float* __restrict__ out)
{
    constexpr int K   = F * CDIM;
    constexpr int KT1 = K / 32;
    constexpr int AS  = K + 8;
    constexpr int YS  = 136;
    __shared__ unsigned short U[64 * AS];   // union: A | Y
    unsigned short* Alds = U;
    unsigned short* Ylds = U;

    const int t  = threadIdx.x;
    const int n0 = blockIdx.x * 64;
    {
        const int rl = t >> 2, q = t & 3;
        const int n  = n0 + rl;
        const bool nv = (n < NCELLS);
        const int nc = nv ? n : (NCELLS - 1);
        unsigned short* arow = Alds + rl * AS;
        // f part: f32 -> bf16
        {
            const float4* sp = (const float4*)(f + (size_t)nc * CDIM + q * 32);
#pragma unroll
            for (int i = 0; i < 4; i++) {
                float4 a = sp[2 * i], b = sp[2 * i + 1];
                uint4 o;
                o.x = pkbf(a.x, a.y); o.y = pkbf(a.z, a.w);
                o.z = pkbf(b.x, b.y); o.w = pkbf(b.z, b.w);
                *(uint4*)(arow + q * 32 + i * 8) = o;
            }
        }
        // message segment sums (2-deep pipelined)
#pragma unroll
        for (int p = 1; p < F; p++) {
            const unsigned short* msg = (p == 1) ? m1 : m2;
            const int* offs = (p == 1) ? o1 : o2;
            int s = 0, e = 0;
            if (nv) { s = offs[n]; e = offs[n + 1]; }
            float accv[32];
#pragma unroll
            for (int i = 0; i < 32; i++) accv[i] = 0.f;
            const uint4* mp = (const uint4*)(msg + (size_t)s * CDIM + q * 32);
            uint4 c0, c1, c2, c3;
            if (s < e) { c0 = mp[0]; c1 = mp[1]; c2 = mp[2]; c3 = mp[3]; }
            for (int k = s; k < e; ++k) {
                const uint4* np = mp + 16;   // next row (CDIM shorts = 16 uint4)
                uint4 n0v, n1v, n2v, n3v;
                if (k + 1 < e) { n0v = np[0]; n1v = np[1]; n2v = np[2]; n3v = np[3]; }
                accum8(accv + 0,  c0);
                accum8(accv + 8,  c1);
                accum8(accv + 16, c2);
                accum8(accv + 24, c3);
                c0 = n0v; c1 = n1v; c2 = n2v; c3 = n3v;
                mp = np;
            }
            unsigned* dst32 = (unsigned*)(arow + p * CDIM + q * 32);
#pragma unroll
            for (int wds = 0; wds < 16; wds++)
                dst32[wds] = pkbf(siluf(accv[2 * wds]), siluf(accv[2 * wds + 1]));
        }
    }
    __syncthreads();

    const int wave = t >> 6, lane = t & 63;
    const int wr = (wave & 1) * 32;
    const int wc = (wave >> 1) * 64;
    const int lr = lane & 15, lg = lane >> 4;

    f32x4 a1[2][4];
#pragma unroll
    for (int mt = 0; mt < 2; mt++)
#pragma unroll
        for (int ct = 0; ct < 4; ct++) a1[mt][ct] = (f32x4){0.f, 0.f, 0.f, 0.f};

    for (int kt = 0; kt < KT1; ++kt) {
        short8 av[2];
#pragma unroll
        for (int mt = 0; mt < 2; mt++)
            av[mt] = *(const short8*)(Alds + (wr + mt * 16 + lr) * AS + kt * 32 + lg * 8);
#pragma unroll
        for (int ct = 0; ct < 4; ct++) {
            const int cg = (wc >> 4) + ct;
            short8 bv = *(const short8*)(W1T + ((size_t)(cg * KT1 + kt) * 64 + lane) * 8);
            a1[0][ct] = __builtin_amdgcn_mfma_f32_16x16x32_bf16(av[0], bv, a1[0][ct], 0, 0, 0);
            a1[1][ct] = __builtin_amdgcn_mfma_f32_16x16x32_bf16(av[1], bv, a1[1][ct], 0, 0, 0);
        }
    }
    __syncthreads();   // A consumed; Y overwrites

#pragma unroll
    for (int ct = 0; ct < 4; ct++) {
        const int col = wc + ct * 16 + lr;
        const float bb = b1[col];
#pragma unroll
        for (int mt = 0; mt < 2; mt++)
#pragma unroll
            for (int j = 0; j < 4; j++) {
                const int row = wr + mt * 16 + lg * 4 + j;
                Ylds[row * YS + col] = cvt1bf(siluf(a1[mt][ct][j] + bb));
            }
    }
    __syncthreads();

    f32x4 a2[2][4];
#pragma unroll
    for (int mt = 0; mt < 2; mt++)
#pragma unroll
        for (int ct = 0; ct < 4; ct++) a2[mt][ct] = (f32x4){0.f, 0.f, 0.f, 0.f};

    for (int kt = 0; kt < 4; ++kt) {
        short8 av[2];
#pragma unroll
        for (int mt = 0; mt < 2; mt++)
            av[mt] = *(const short8*)(Ylds + (wr + mt * 16 + lr) * YS + kt * 32 + lg * 8);
#pragma unroll
        for (int ct = 0; ct < 4; ct++) {
            const int cg = (wc >> 4) + ct;
            short8 bv = *(const short8*)(W2T + ((size_t)(cg * 4 + kt) * 64 + lane) * 8);
            a2[0][ct] = __builtin_amdgcn_mfma_f32_16x16x32_bf16(av[0], bv, a2[0][ct], 0, 0, 0);
            a2[1][ct] = __builtin_amdgcn_mfma_f32_16x16x32_bf16(av[1], bv, a2[1][ct], 0, 0, 0);
        }
    }

    float b2c[4];
#pragma unroll
    for (int ct = 0; ct < 4; ct++) b2c[ct] = b2[wc + ct * 16 + lr];

#pragma unroll
    for (int mt = 0; mt < 2; mt++)
#pragma unroll
        for (int j = 0; j < 4; j++) {
            const int row = wr + mt * 16 + lg * 4 + j;
            const int n2  = n0 + row;
            if (n2 < NCELLS) {
#pragma unroll
                for (int ct = 0; ct < 4; ct++) {
                    const int col = wc + ct * 16 + lr;
                    out[(size_t)n2 * CDIM + col] =
                        f[(size_t)n2 * CDIM + col] + a2[mt][ct][j] + b2c[ct];
                }
            }
        }
}

// ---------------------------------------------------------------------------
extern "C" void kernel_launch(void* const* d_in, const int* in_sizes, int n_in,
                              void* d_out, int out_size, void* d_ws, size_t ws_size,
                              hipStream_t stream)
{
    const float* f0 = (const float*)d_in[0];
    const float* f1 = (const float*)d_in[1];
    const float* f2 = (const float*)d_in[2];

    const int*   a0_send = (const int*)d_in[3];
    const int*   a0_recv = (const int*)d_in[4];
    const float* inv_a0  = (const float*)d_in[5];
    const float* a0_b1   = (const float*)d_in[7];
    const float* a0_b2   = (const float*)d_in[9];
    const float* a0_Wg   = (const float*)d_in[10];
    const float* a0_bg   = (const float*)d_in[11];

    const int*   a1_send = (const int*)d_in[12];
    const int*   a1_recv = (const int*)d_in[13];
    const float* inv_a1  = (const float*)d_in[14];
    const float* a1_b1   = (const float*)d_in[16];
    const float* a1_b2   = (const float*)d_in[18];
    const float* a1_Wg   = (const float*)d_in[19];
    const float* a1_bg   = (const float*)d_in[20];

    const int*   i1_send = (const int*)d_in[21];
    const int*   i1_recv = (const int*)d_in[22];
    const float* inv_i1  = (const float*)d_in[23];
    const float* i1_b1   = (const float*)d_in[25];
    const float* i1_b2   = (const float*)d_in[27];
    const float* i1_Wg   = (const float*)d_in[28];
    const float* i1_bg   = (const float*)d_in[29];

    const int*   i2_send = (const int*)d_in[30];
    const int*   i2_recv = (const int*)d_in[31];
    const float* inv_i2  = (const float*)d_in[32];
    const float* i2_b1   = (const float*)d_in[34];
    const float* i2_b2   = (const float*)d_in[36];
    const float* i2_Wg   = (const float*)d_in[37];
    const float* i2_bg   = (const float*)d_in[38];

    const float* u0_b1 = (const float*)d_in[40];
    const float* u0_b2 = (const float*)d_in[42];
    const float* u1_b1 = (const float*)d_in[44];
    const float* u1_b2 = (const float*)d_in[46];
    const float* u2_b1 = (const float*)d_in[48];
    const float* u2_b2 = (const float*)d_in[50];

    const int E_a0 = in_sizes[3];
    const int E_a1 = in_sizes[12];
    const int E_i1 = in_sizes[21];
    const int E_i2 = in_sizes[30];

    // ---- ws bump allocator ----
    char* base = (char*)d_ws;
    size_t off = 0;
    auto alloc = [&](size_t bytes) -> char* {
        off = (off + 255) & ~(size_t)255;
        char* p = base + off;
        off += bytes;
        return p;
    };
    unsigned short* wb  = (unsigned short*)alloc(753664);
    int* offs_all = (int*)alloc((size_t)4 * (NCELLS + 1) * sizeof(int));
    int* bins_all = (int*)alloc((size_t)4 * NCELLS * sizeof(int));   // also cursor
    int* pos0 = (int*)alloc((size_t)E_a0 * sizeof(int));
    int* pos1 = (int*)alloc((size_t)E_a1 * sizeof(int));
    int* pos2 = (int*)alloc((size_t)E_i1 * sizeof(int));
    int* pos3 = (int*)alloc((size_t)E_i2 * sizeof(int));
    unsigned short* msgA = (unsigned short*)alloc((size_t)400000 * CDIM * sizeof(unsigned short));
    unsigned short* msgB = (unsigned short*)alloc((size_t)200000 * CDIM * sizeof(unsigned short));
    unsigned short* PsT  = (unsigned short*)alloc((size_t)NCELLS * CDIM * sizeof(unsigned short));
    unsigned short* PtT  = (unsigned short*)alloc((size_t)NCELLS * CDIM * sizeof(unsigned short));

    // ---- weight prep ----
    const int o_w1[4]  = {0, 36864, 73728, 110592};
    const int o_w2[4]  = {147456, 163840, 180224, 196608};
    const int o_uw1[3] = {212992, 245760, 294912};
    const int o_uw2[3] = {327680, 344064, 360448};

    PrepArgs pa;
    int idx = 0, cum = 0;
    auto add = [&](const void* s, int fin, int ktc, int woff) {
        pa.src[idx] = (const float*)s; pa.fin[idx] = fin; pa.ktc[idx] = ktc;
        pa.dstoff[idx] = woff; cum += ktc * 8; pa.tend[idx] = cum; idx++;
    };
    add(d_in[6],  259, 9,  o_w1[0]);
    add(d_in[15], 262, 9,  o_w1[1]);
    add(d_in[24], 259, 9,  o_w1[2]);
    add(d_in[33], 262, 9,  o_w1[3]);
    add(d_in[8],  128, 4,  o_w2[0]);
    add(d_in[17], 128, 4,  o_w2[1]);
    add(d_in[26], 128, 4,  o_w2[2]);
    add(d_in[35], 128, 4,  o_w2[3]);
    add(d_in[39], 256, 8,  o_uw1[0]);
    add(d_in[43], 384, 12, o_uw1[1]);
    add(d_in[47], 256, 8,  o_uw1[2]);
    add(d_in[41], 128, 4,  o_uw2[0]);
    add(d_in[45], 128, 4,  o_uw2[1]);
    add(d_in[49], 128, 4,  o_uw2[2]);
    prep_kernel<<<cum, 64, 0, stream>>>(pa, wb);

    // ---- CSR build ----
    const int Etot = E_a0 + E_a1 + E_i1 + E_i2;
    hipMemsetAsync(bins_all, 0, (size_t)4 * NCELLS * sizeof(int), stream);
    hist4_kernel<<<(Etot + 255) / 256, 256, 0, stream>>>(
        a0_recv, a1_recv, i1_recv, i2_recv, E_a0, E_a1, E_i1, E_i2, bins_all);
    scan_kernel<<<4, 1024, 0, stream>>>(bins_all, offs_all, NCELLS);
    hipMemsetAsync(bins_all, 0, (size_t)4 * NCELLS * sizeof(int), stream);
    rank4_kernel<<<(Etot + 255) / 256, 256, 0, stream>>>(
        a0_recv, a1_recv, i1_recv, i2_recv, E_a0, E_a1, E_i1, E_i2,
        offs_all, bins_all, pos0, pos1, pos2, pos3);

    const int* offs0 = offs_all;
    const int* offs1 = offs_all + (size_t)1 * (NCELLS + 1);
    const int* offs2 = offs_all + (size_t)2 * (NCELLS + 1);
    const int* offs3 = offs_all + (size_t)3 * (NCELLS + 1);

    float* out = (float*)d_out;
    const int UPD_BLK = (NCELLS + 63) / 64;
    const int PG_BLK  = UPD_BLK;

    // rank 0: a0
    pgemm_kernel<<<PG_BLK, 256, 0, stream>>>(f0, wb + o_w1[0], 0, nullptr, PsT);
    pgemm_kernel<<<PG_BLK, 256, 0, stream>>>(f0, wb + o_w1[0], 4, a0_b1, PtT);
    econv_kernel<3><<<(E_a0 + 63) / 64, 256, 0, stream>>>(
        PsT, PtT, a0_send, a0_recv, inv_a0,
        wb + o_w1[0], wb + o_w2[0], a0_b2, a0_Wg, a0_bg, pos0, msgA, E_a0);
    update_kernel<2><<<UPD_BLK, 256, 0, stream>>>(
        f0, msgA, offs0, nullptr, nullptr,
        wb + o_uw1[0], u0_b1, wb + o_uw2[0], u0_b2, out);

    // rank 1: a1 then i1
    pgemm_kernel<<<PG_BLK, 256, 0, stream>>>(f1, wb + o_w1[1], 0, nullptr, PsT);
    pgemm_kernel<<<PG_BLK, 256, 0, stream>>>(f1, wb + o_w1[1], 4, a1_b1, PtT);
    econv_kernel<6><<<(E_a1 + 63) / 64, 256, 0, stream>>>(
        PsT, PtT, a1_send, a1_recv, inv_a1,
        wb + o_w1[1], wb + o_w2[1], a1_b2, a1_Wg, a1_bg, pos1, msgA, E_a1);
    pgemm_kernel<<<PG_BLK, 256, 0, stream>>>(f0, wb + o_w1[2], 0, nullptr, PsT);
    pgemm_kernel<<<PG_BLK, 256, 0, stream>>>(f1, wb + o_w1[2], 4, i1_b1, PtT);
    econv_kernel<3><<<(E_i1 + 63) / 64, 256, 0, stream>>>(
        PsT, PtT, i1_send, i1_recv, inv_i1,
        wb + o_w1[2], wb + o_w2[2], i1_b2, i1_Wg, i1_bg, pos2, msgB, E_i1);
    update_kernel<3><<<UPD_BLK, 256, 0, stream>>>(
        f1, msgA, offs1, msgB, offs2,
        wb + o_uw1[1], u1_b1, wb + o_uw2[1], u1_b2, out + (size_t)NCELLS * CDIM);

    // rank 2: i2
    pgemm_kernel<<<PG_BLK, 256, 0, stream>>>(f1, wb + o_w1[3], 0, nullptr, PsT);
    pgemm_kernel<<<PG_BLK, 256, 0, stream>>>(f2, wb + o_w1[3], 4, i2_b1, PtT);
    econv_kernel<6><<<(E_i2 + 63) / 64, 256, 0, stream>>>(
        PsT, PtT, i2_send, i2_recv, inv_i2,
        wb + o_w1[3], wb + o_w2[3], i2_b2, i2_Wg, i2_bg, pos3, msgA, E_i2);
    update_kernel<2><<<UPD_BLK, 256, 0, stream>>>(
        f2, msgA, offs3, nullptr, nullptr,
        wb + o_uw1[2], u2_b1, wb + o_uw2[2], u2_b2, out + 2 * (size_t)NCELLS * CDIM);
}